// Round 5
// baseline (814.009 us; speedup 1.0000x reference)
//
#include <hip/hip_runtime.h>
#include <math.h>

#define NNODES 50000
#define DEGREE 16
#define NGRAPH 64
#define CAP 64
#define LDA 136   // padded LDS stride (bf16 elems)
#define NXCD 8
#define XRANGE (NNODES / NXCD)      // 6250
#define FCHUNK 2048                 // edges per fill task
#define NCH ((NNODES * DEGREE + FCHUNK - 1) / FCHUNK)   // 391

typedef unsigned short u16;
typedef unsigned int u32;
typedef unsigned long long u64;
using short8 = __attribute__((ext_vector_type(8))) short;
using f32x4  = __attribute__((ext_vector_type(4))) float;
using u16x4  = __attribute__((ext_vector_type(4))) unsigned short;

__device__ __forceinline__ u16 f2bf(float f) {
  union { float f; u32 u; } v; v.f = f;
  u32 u = v.u;
  return (u16)((u + 0x7FFFu + ((u >> 16) & 1u)) >> 16);   // RNE
}
__device__ __forceinline__ float bf2f(u16 h) {
  union { u32 u; float f; } v; v.u = ((u32)h) << 16;
  return v.f;
}
__device__ __forceinline__ float2 bf2x2(u32 u) {
  union { u32 u; float f; } lo, hi;
  lo.u = (u & 0xFFFFu) << 16; hi.u = u & 0xFFFF0000u;
  return make_float2(lo.f, hi.f);
}
__device__ __forceinline__ u32 pack2(float x, float y) {
  return (u32)f2bf(x) | ((u32)f2bf(y) << 16);
}

__device__ __forceinline__ int lowerb(const int* b, int n, int v) {
  int lo = 0, hi = n;
  while (lo < hi) { int m = (lo + hi) >> 1; if (b[m] < v) lo = m + 1; else hi = m; }
  return lo;
}

// fused: ew=1, agg0[n]=sum of 16 edge_attr; x fp32 -> bf16
__global__ void k_init(const float* __restrict__ eattr, const float* __restrict__ x,
                       float* __restrict__ ew, float* __restrict__ agg0,
                       u16* __restrict__ xb) {
  int i = blockIdx.x * blockDim.x + threadIdx.x;
  if (i < NNODES * 32) {
    float4 v = reinterpret_cast<const float4*>(x)[i];
    u16x4 o = {f2bf(v.x), f2bf(v.y), f2bf(v.z), f2bf(v.w)};
    reinterpret_cast<u16x4*>(xb)[i] = o;
  }
  if (i < NNODES) {
    const float4* p = reinterpret_cast<const float4*>(eattr + (size_t)i * DEGREE);
    float s = 0.f;
#pragma unroll
    for (int j = 0; j < 4; ++j) { float4 v = p[j]; s += v.x + v.y + v.z + v.w; }
    agg0[i] = s;
    ew[i] = 1.0f;
  }
}

// all 4 weight matrices fp32[k][n] -> bf16 transposed [which][n][k], one launch
__global__ void k_cvtW4(const float* __restrict__ W0, const float* __restrict__ W1,
                        const float* __restrict__ W2, const float* __restrict__ W3,
                        u16* __restrict__ Wt) {
  int idx = blockIdx.x * blockDim.x + threadIdx.x;
  if (idx >= 4 * 128 * 128) return;
  int which = idx >> 14, r = idx & 16383;
  int k = r >> 7, n = r & 127;
  const float* W = which == 0 ? W0 : which == 1 ? W1 : which == 2 ? W2 : W3;
  Wt[which * 16384 + n * 128 + k] = f2bf(W[k * 128 + n]);
}

// out[M,128](bf16) = A(bf16) @ W  (+bias, relu optional)
// egmode: A row r = alpha * relu(agg0[r]*weg + beg)
__global__ __launch_bounds__(256) void k_gemm_mfma(
    const u16* __restrict__ A, const u16* __restrict__ Wt,
    const float* __restrict__ bias, u16* __restrict__ out,
    int M, int relu, int egmode, float alpha,
    const float* __restrict__ agg0, const float* __restrict__ weg,
    const float* __restrict__ beg) {
  __shared__ u16 Bs[128 * LDA];
  __shared__ u16 As[64 * LDA];
  int t = threadIdx.x;
  for (int i = t; i < 2048; i += 256) {
    int r = i >> 4, c = (i & 15) << 3;
    *reinterpret_cast<uint4*>(&Bs[r * LDA + c]) =
        *reinterpret_cast<const uint4*>(&Wt[r * 128 + c]);
  }
  int m0 = blockIdx.x * 64;
  if (egmode) {
    for (int idx = t; idx < 64 * 128; idx += 256) {
      int r = idx >> 7, k = idx & 127;
      int row = m0 + r;
      float a = (row < M) ? agg0[row] : 0.f;
      float v = alpha * fmaxf(fmaf(a, weg[k], beg[k]), 0.f);
      As[r * LDA + k] = f2bf(v);
    }
  } else {
    for (int i = t; i < 1024; i += 256) {
      int r = i >> 4, c = (i & 15) << 3;
      int row = m0 + r;
      uint4 v = make_uint4(0u, 0u, 0u, 0u);
      if (row < M) v = *reinterpret_cast<const uint4*>(&A[(size_t)row * 128 + c]);
      *reinterpret_cast<uint4*>(&As[r * LDA + c]) = v;
    }
  }
  __syncthreads();
  int wave = t >> 6, lane = t & 63;
  int lm = lane & 15, quad = lane >> 4;
  f32x4 z = {0.f, 0.f, 0.f, 0.f};
  f32x4 acc[8];
#pragma unroll
  for (int n = 0; n < 8; ++n) acc[n] = z;
  const u16* arow = &As[(wave * 16 + lm) * LDA + quad * 8];
#pragma unroll
  for (int kc = 0; kc < 4; ++kc) {
    short8 af = *reinterpret_cast<const short8*>(arow + kc * 32);
#pragma unroll
    for (int n = 0; n < 8; ++n) {
      short8 bf = *reinterpret_cast<const short8*>(
          &Bs[(n * 16 + lm) * LDA + kc * 32 + quad * 8]);
      acc[n] = __builtin_amdgcn_mfma_f32_16x16x32_bf16(af, bf, acc[n], 0, 0, 0);
    }
  }
  // C/D layout: col = lane&15, row = quad*4 + reg
#pragma unroll
  for (int n = 0; n < 8; ++n) {
    int col = n * 16 + lm;
    float bv = bias ? bias[col] : 0.f;
#pragma unroll
    for (int r = 0; r < 4; ++r) {
      int row = m0 + wave * 16 + quad * 4 + r;
      if (row < M) {
        float v = acc[n][r] + bv;
        if (relu) v = fmaxf(v, 0.f);
        out[(size_t)row * 128 + col] = f2bf(v);
      }
    }
  }
}

// XCD-partitioned bucketing: dst range r belongs to XCD r; blocks claim
// (range, edge-chunk) tasks from per-range counters, own-range first, then
// steal (correct under ANY workgroup->XCD dispatch; XCC_ID only steers
// locality so slots/cnt lines stay in ONE L2 -> no cross-XCD line ping-pong).
// Entry stored is just the edge index e == (src<<4)|slot_j.
__global__ __launch_bounds__(256) void k_fill(
    const int* __restrict__ edst, int* __restrict__ cnt,
    int* __restrict__ slots, int* __restrict__ next) {
  int xcc = __builtin_amdgcn_s_getreg(6164) & 7;   // hwreg(HW_REG_XCC_ID,0,4)
  int lane = threadIdx.x & 63;
  for (int t = 0; t < NXCD; ++t) {
    int r = (xcc + t) & 7;
    int rlo = r * XRANGE, rhi = rlo + XRANGE;
    while (true) {
      int c = 0;
      if (lane == 0) c = atomicAdd(&next[r], 1);
      c = __shfl(c, 0, 64);
      if (c >= NCH) break;
      int e0 = c * FCHUNK;
#pragma unroll 4
      for (int i = 0; i < FCHUNK / 64; ++i) {
        int e = e0 + i * 64 + lane;
        if (e < NNODES * DEGREE) {
          int d = edst[e];
          if (d >= rlo && d < rhi) {
            int pos = atomicAdd(&cnt[d], 1);
            if (pos < CAP) slots[(size_t)d * CAP + pos] = e;
          }
        }
      }
    }
  }
}

// wave per node: dinv[n]=rsqrt(1+sum_{kept} ew[src]); wsrc[n]=dinv[n]*ew[n]
// first=1 (layer 0): all ew==1 -> no gather needed
__global__ __launch_bounds__(256) void k_dinv(
    const int* __restrict__ cnt, const int* __restrict__ slots,
    const float* __restrict__ ew, float* __restrict__ dinv,
    float* __restrict__ wsrc, int keep, int first) {
  int n = (int)((blockIdx.x * blockDim.x + threadIdx.x) >> 6);
  int lane = threadIdx.x & 63;
  if (n >= NNODES) return;
  int c = min(cnt[n], CAP);
  float e = 0.f;
  if (first) {
    e = (lane < c) ? 1.f : 0.f;
  } else {
    u32 ent = 0;
    if (lane < c) ent = (u32)slots[(size_t)n * CAP + lane];
    if (lane < c && (ent & 15u) < (u32)keep) e = ew[ent >> 4];
  }
#pragma unroll
  for (int m = 32; m >= 1; m >>= 1) e += __shfl_xor(e, m, 64);
  float d = rsqrtf(1.0f + e);
  if (lane == 0) { dinv[n] = d; wsrc[n] = first ? d : d * ew[n]; }
}

// h[n] = relu( dinv[n]*sum_{kept} wsrc[src]*xw[src] + dinv[n]^2*xw[n] + b )
// keep<16: ballot + ds_permute compaction so gathers touch only kept edges.
// 8-deep software pipeline: 8 independent row loads in flight per wave.
__global__ __launch_bounds__(256) void k_agg(
    const u16* __restrict__ xwb, const int* __restrict__ cnt,
    const int* __restrict__ slots, const float* __restrict__ wsrc,
    const float* __restrict__ dinv, const float* __restrict__ bias,
    u16* __restrict__ hout, int keep) {
  int n = (int)((blockIdx.x * blockDim.x + threadIdx.x) >> 6);
  int lane = threadIdx.x & 63;
  if (n >= NNODES) return;
  int c = min(cnt[n], CAP);
  u32 e = 0;
  if (lane < c) e = (u32)slots[(size_t)n * CAP + lane];
  int kc; u32 ce;
  if (keep < 16) {
    bool valid = (lane < c) && ((e & 15u) < (u32)keep);
    u64 mask = __ballot(valid);
    kc = (int)__popcll(mask);
    u64 lt = ((u64)1 << lane) - 1;
    // collision-free permutation: valid lanes pack to [0,kc), invalid to (63..kc]
    int pos = valid ? (int)__popcll(mask & lt) : 63 - (int)__popcll((~mask) & lt);
    ce = (u32)__builtin_amdgcn_ds_permute(pos << 2, (int)e);
  } else { kc = c; ce = e; }
  int sl = 0; float wl = 0.f;
  if (lane < kc) {
    sl = (int)(ce >> 4);
    wl = wsrc[sl];
  }
  const u32* base = reinterpret_cast<const u32*>(xwb);
  float2 acc = make_float2(0.f, 0.f);
  int i = 0;
  for (; i + 8 <= kc; i += 8) {
    u32 r[8]; float w[8];
#pragma unroll
    for (int j = 0; j < 8; ++j) {
      int s = __shfl(sl, i + j, 64);
      w[j] = __shfl(wl, i + j, 64);
      r[j] = base[(size_t)s * 64 + lane];
    }
#pragma unroll
    for (int j = 0; j < 8; ++j) {
      float2 v = bf2x2(r[j]);
      acc.x = fmaf(w[j], v.x, acc.x);
      acc.y = fmaf(w[j], v.y, acc.y);
    }
  }
  for (; i + 4 <= kc; i += 4) {
    u32 r[4]; float w[4];
#pragma unroll
    for (int j = 0; j < 4; ++j) {
      int s = __shfl(sl, i + j, 64);
      w[j] = __shfl(wl, i + j, 64);
      r[j] = base[(size_t)s * 64 + lane];
    }
#pragma unroll
    for (int j = 0; j < 4; ++j) {
      float2 v = bf2x2(r[j]);
      acc.x = fmaf(w[j], v.x, acc.x);
      acc.y = fmaf(w[j], v.y, acc.y);
    }
  }
  for (; i < kc; ++i) {
    int s = __shfl(sl, i, 64);
    float w = __shfl(wl, i, 64);
    float2 v = bf2x2(base[(size_t)s * 64 + lane]);
    acc.x = fmaf(w, v.x, acc.x);
    acc.y = fmaf(w, v.y, acc.y);
  }
  float di = dinv[n];
  float2 self = bf2x2(base[(size_t)n * 64 + lane]);
  float2 b = reinterpret_cast<const float2*>(bias)[lane];
  float rx = fmaxf(fmaf(di, acc.x, fmaf(di * di, self.x, b.x)), 0.f);
  float ry = fmaxf(fmaf(di, acc.y, fmaf(di * di, self.y, b.y)), 0.f);
  reinterpret_cast<u32*>(hout + (size_t)n * 128)[lane] = pack2(rx, ry);
}

// layer-0 score: ew[n] = clip(tanh(16*dot(relu(agg0*weg0+beg0), wsc0)+bsc0),0,1)
__global__ void k_score0(const float* __restrict__ agg0, const float* __restrict__ weg,
                         const float* __restrict__ beg, const float* __restrict__ wsc,
                         const float* __restrict__ bsc, float* __restrict__ ew) {
  int n = blockIdx.x * blockDim.x + threadIdx.x;
  if (n >= NNODES) return;
  float a = agg0[n];
  float s = 0.f;
  for (int k = 0; k < 128; ++k) {
    float e = fmaxf(fmaf(a, weg[k], beg[k]), 0.f);
    s = fmaf(e, wsc[k], s);
  }
  float sc = tanhf(fmaf(16.f, s, bsc[0]));
  ew[n] = fminf(fmaxf(sc, 0.f), 1.f);
}

// layer-1 score from ea2 (bf16): ew[n] = clip(tanh(scale*dot(ea2[n], wsc1)+bsc1),0,1)
__global__ __launch_bounds__(256) void k_score1(
    const u16* __restrict__ ea2, const float* __restrict__ wsc,
    const float* __restrict__ bsc, float scale, float* __restrict__ ew) {
  int wave = (int)((blockIdx.x * blockDim.x + threadIdx.x) >> 6);
  int lane = threadIdx.x & 63;
  if (wave >= NNODES) return;
  float2 v = bf2x2(reinterpret_cast<const u32*>(ea2 + (size_t)wave * 128)[lane]);
  float2 w = reinterpret_cast<const float2*>(wsc)[lane];
  float s = fmaf(v.x, w.x, v.y * w.y);
#pragma unroll
  for (int m = 32; m >= 1; m >>= 1) s += __shfl_xor(s, m, 64);
  if (lane == 0) {
    float sc = tanhf(fmaf(scale, s, bsc[0]));
    ew[wave] = fminf(fmaxf(sc, 0.f), 1.f);
  }
}

// pooling stage A: 16 slices per graph -> partial max/sum per feature (bf16 input)
__global__ __launch_bounds__(256) void k_poolA(
    const u16* __restrict__ h, const int* __restrict__ batch,
    float* __restrict__ pmax, float* __restrict__ psum) {
  __shared__ float smx[256], ssm[256];
  int g = blockIdx.x >> 4, sl = blockIdx.x & 15;
  int lo = lowerb(batch, NNODES, g);
  int hi = lowerb(batch, NNODES, g + 1);
  int len = hi - lo;
  int start = lo + (len * sl) / 16;
  int end = lo + (len * (sl + 1)) / 16;
  int f = threadIdx.x & 127, half = threadIdx.x >> 7;
  float mx = -3.402823466e38f, sm = 0.f;
  for (int n = start + half; n < end; n += 2) {
    float v = bf2f(h[(size_t)n * 128 + f]);
    mx = fmaxf(mx, v);
    sm += v;
  }
  smx[threadIdx.x] = mx; ssm[threadIdx.x] = sm;
  __syncthreads();
  if (threadIdx.x < 128) {
    mx = fmaxf(smx[threadIdx.x], smx[threadIdx.x + 128]);
    sm = ssm[threadIdx.x] + ssm[threadIdx.x + 128];
    pmax[(size_t)blockIdx.x * 128 + threadIdx.x] = mx;
    psum[(size_t)blockIdx.x * 128 + threadIdx.x] = sm;
  }
}

// pooling stage B: combine 16 slices, accumulate [gmax|gmean|gsum] into out
__global__ void k_poolB(const float* __restrict__ pmax, const float* __restrict__ psum,
                        const int* __restrict__ batch, float* __restrict__ out) {
  int g = blockIdx.x, f = threadIdx.x;
  float mx = -3.402823466e38f, sm = 0.f;
  for (int s = 0; s < 16; ++s) {
    mx = fmaxf(mx, pmax[(size_t)(g * 16 + s) * 128 + f]);
    sm += psum[(size_t)(g * 16 + s) * 128 + f];
  }
  int lo = lowerb(batch, NNODES, g);
  int hi = lowerb(batch, NNODES, g + 1);
  float cntf = (float)(hi - lo);
  out[g * 384 + f] += mx;
  out[g * 384 + 128 + f] += sm / cntf;
  out[g * 384 + 256 + f] += sm;
}

extern "C" void kernel_launch(void* const* d_in, const int* in_sizes, int n_in,
                              void* d_out, int out_size, void* d_ws, size_t ws_size,
                              hipStream_t stream) {
  const float* x     = (const float*)d_in[0];
  const float* eattr = (const float*)d_in[1];
  const int*   edst  = (const int*)d_in[3];
  const int*   batch = (const int*)d_in[4];
  const float* Wg0 = (const float*)d_in[5];  const float* bg0 = (const float*)d_in[6];
  const float* Wg1 = (const float*)d_in[7];  const float* bg1 = (const float*)d_in[8];
  const float* Wg2 = (const float*)d_in[9];  const float* bg2 = (const float*)d_in[10];
  const float* We0 = (const float*)d_in[11]; const float* be0 = (const float*)d_in[12];
  const float* We1 = (const float*)d_in[13]; const float* be1 = (const float*)d_in[14];
  const float* Ws0 = (const float*)d_in[15]; const float* bs0 = (const float*)d_in[16];
  const float* Ws1 = (const float*)d_in[17]; const float* bs1 = (const float*)d_in[18];
  float* out = (float*)d_out;

  char* ws = (char*)d_ws;
  const size_t NBH = (size_t)NNODES * 128 * 2;   // 12.8 MB bf16 node-feature block
  size_t off = 0;
  auto alloc = [&](size_t bytes) { void* p = ws + off; off = (off + bytes + 255) & ~(size_t)255; return p; };
  u16*   Xb    = (u16*)alloc(NBH);
  u16*   XWb   = (u16*)alloc(NBH);
  u16*   Hb    = (u16*)alloc(NBH);
  u16*   Wtb   = (u16*)alloc(4 * 128 * 128 * 2);
  int*   slots = (int*)alloc((size_t)NNODES * CAP * 4);
  int*   cnt   = (int*)alloc((size_t)NNODES * 4);
  int*   next  = (int*)alloc(NXCD * 4);
  float* agg0  = (float*)alloc((size_t)NNODES * 4);
  float* ew    = (float*)alloc((size_t)NNODES * 4);
  float* dinv  = (float*)alloc((size_t)NNODES * 4);
  float* wsrc  = (float*)alloc((size_t)NNODES * 4);
  float* pmax  = (float*)alloc((size_t)NGRAPH * 16 * 128 * 4);
  float* psum  = (float*)alloc((size_t)NGRAPH * 16 * 128 * 4);

  hipMemsetAsync(d_out, 0, (size_t)out_size * sizeof(float), stream);
  hipMemsetAsync(cnt, 0, (size_t)NNODES * 4, stream);
  hipMemsetAsync(next, 0, NXCD * 4, stream);
  int nblkN = (NNODES + 255) / 256;
  k_init<<<(NNODES * 32 + 255) / 256, 256, 0, stream>>>(eattr, x, ew, agg0, Xb);
  k_cvtW4<<<(4 * 16384 + 255) / 256, 256, 0, stream>>>(Wg0, Wg1, Wg2, We1, Wtb);
  // ONE bucketing pass for all 3 layers (edge sets are slot-prefixes), XCD-local
  k_fill<<<1024, 256, 0, stream>>>(edst, cnt, slots, next);

  const float* bg[3] = {bg0, bg1, bg2};
  const int keep[3] = {16, 8, 4};
  const int ntile = (NNODES + 63) / 64;   // 782
  const u16* hin = Xb;
  for (int L = 0; L < 3; ++L) {
    k_gemm_mfma<<<ntile, 256, 0, stream>>>(hin, Wtb + (size_t)L * 16384, nullptr, XWb,
                                           NNODES, 0, 0, 1.f, nullptr, nullptr, nullptr);
    k_dinv<<<(NNODES + 3) / 4, 256, 0, stream>>>(cnt, slots, ew, dinv, wsrc,
                                                 keep[L], L == 0 ? 1 : 0);
    k_agg<<<(NNODES + 3) / 4, 256, 0, stream>>>(XWb, cnt, slots, wsrc, dinv, bg[L],
                                                Hb, keep[L]);
    k_poolA<<<NGRAPH * 16, 256, 0, stream>>>(Hb, batch, pmax, psum);
    k_poolB<<<NGRAPH, 128, 0, stream>>>(pmax, psum, batch, out);
    if (L == 0) {
      k_score0<<<nblkN, 256, 0, stream>>>(agg0, We0, be0, Ws0, bs0, ew);
    } else if (L == 1) {
      // ea2 = relu((8*ea1) @ W_eg1 + b_eg1), ea1 regenerated from agg0 in-kernel
      k_gemm_mfma<<<ntile, 256, 0, stream>>>(nullptr, Wtb + 3 * 16384, be1, XWb,
                                             NNODES, 1, 1, 8.f, agg0, We0, be0);
      // ew for layer 2: clip(tanh(8*ea2.wsc1 + bsc1))
      k_score1<<<(NNODES + 3) / 4, 256, 0, stream>>>(XWb, Ws1, bs1, 8.f, ew);
    }
    hin = Hb;
  }
}

// Round 6
// 415.816 us; speedup vs baseline: 1.9576x; 1.9576x over previous
//
#include <hip/hip_runtime.h>
#include <math.h>

#define NNODES 50000
#define DEGREE 16
#define NGRAPH 64
#define CAP 64
#define LDA 136   // padded LDS stride (bf16 elems)
#define NXCD 8
#define XRANGE (NNODES / NXCD)      // 6250 dst nodes per range

typedef unsigned short u16;
typedef unsigned int u32;
typedef unsigned long long u64;
using short8 = __attribute__((ext_vector_type(8))) short;
using f32x4  = __attribute__((ext_vector_type(4))) float;
using u16x4  = __attribute__((ext_vector_type(4))) unsigned short;

__device__ __forceinline__ u16 f2bf(float f) {
  union { float f; u32 u; } v; v.f = f;
  u32 u = v.u;
  return (u16)((u + 0x7FFFu + ((u >> 16) & 1u)) >> 16);   // RNE
}
__device__ __forceinline__ float bf2f(u16 h) {
  union { u32 u; float f; } v; v.u = ((u32)h) << 16;
  return v.f;
}
__device__ __forceinline__ float2 bf2x2(u32 u) {
  union { u32 u; float f; } lo, hi;
  lo.u = (u & 0xFFFFu) << 16; hi.u = u & 0xFFFF0000u;
  return make_float2(lo.f, hi.f);
}
__device__ __forceinline__ u32 pack2(float x, float y) {
  return (u32)f2bf(x) | ((u32)f2bf(y) << 16);
}

__device__ __forceinline__ int lowerb(const int* b, int n, int v) {
  int lo = 0, hi = n;
  while (lo < hi) { int m = (lo + hi) >> 1; if (b[m] < v) lo = m + 1; else hi = m; }
  return lo;
}

// fused: ew=1, agg0[n]=sum of 16 edge_attr; x fp32 -> bf16
__global__ void k_init(const float* __restrict__ eattr, const float* __restrict__ x,
                       float* __restrict__ ew, float* __restrict__ agg0,
                       u16* __restrict__ xb) {
  int i = blockIdx.x * blockDim.x + threadIdx.x;
  if (i < NNODES * 32) {
    float4 v = reinterpret_cast<const float4*>(x)[i];
    u16x4 o = {f2bf(v.x), f2bf(v.y), f2bf(v.z), f2bf(v.w)};
    reinterpret_cast<u16x4*>(xb)[i] = o;
  }
  if (i < NNODES) {
    const float4* p = reinterpret_cast<const float4*>(eattr + (size_t)i * DEGREE);
    float s = 0.f;
#pragma unroll
    for (int j = 0; j < 4; ++j) { float4 v = p[j]; s += v.x + v.y + v.z + v.w; }
    agg0[i] = s;
    ew[i] = 1.0f;
  }
}

// all 4 weight matrices fp32[k][n] -> bf16 transposed [which][n][k], one launch
__global__ void k_cvtW4(const float* __restrict__ W0, const float* __restrict__ W1,
                        const float* __restrict__ W2, const float* __restrict__ W3,
                        u16* __restrict__ Wt) {
  int idx = blockIdx.x * blockDim.x + threadIdx.x;
  if (idx >= 4 * 128 * 128) return;
  int which = idx >> 14, r = idx & 16383;
  int k = r >> 7, n = r & 127;
  const float* W = which == 0 ? W0 : which == 1 ? W1 : which == 2 ? W2 : W3;
  Wt[which * 16384 + n * 128 + k] = f2bf(W[k * 128 + n]);
}

// out[M,128](bf16) = A(bf16) @ W  (+bias, relu optional)
// egmode: A row r = alpha * relu(agg0[r]*weg + beg)
__global__ __launch_bounds__(256) void k_gemm_mfma(
    const u16* __restrict__ A, const u16* __restrict__ Wt,
    const float* __restrict__ bias, u16* __restrict__ out,
    int M, int relu, int egmode, float alpha,
    const float* __restrict__ agg0, const float* __restrict__ weg,
    const float* __restrict__ beg) {
  __shared__ u16 Bs[128 * LDA];
  __shared__ u16 As[64 * LDA];
  int t = threadIdx.x;
  for (int i = t; i < 2048; i += 256) {
    int r = i >> 4, c = (i & 15) << 3;
    *reinterpret_cast<uint4*>(&Bs[r * LDA + c]) =
        *reinterpret_cast<const uint4*>(&Wt[r * 128 + c]);
  }
  int m0 = blockIdx.x * 64;
  if (egmode) {
    for (int idx = t; idx < 64 * 128; idx += 256) {
      int r = idx >> 7, k = idx & 127;
      int row = m0 + r;
      float a = (row < M) ? agg0[row] : 0.f;
      float v = alpha * fmaxf(fmaf(a, weg[k], beg[k]), 0.f);
      As[r * LDA + k] = f2bf(v);
    }
  } else {
    for (int i = t; i < 1024; i += 256) {
      int r = i >> 4, c = (i & 15) << 3;
      int row = m0 + r;
      uint4 v = make_uint4(0u, 0u, 0u, 0u);
      if (row < M) v = *reinterpret_cast<const uint4*>(&A[(size_t)row * 128 + c]);
      *reinterpret_cast<uint4*>(&As[r * LDA + c]) = v;
    }
  }
  __syncthreads();
  int wave = t >> 6, lane = t & 63;
  int lm = lane & 15, quad = lane >> 4;
  f32x4 z = {0.f, 0.f, 0.f, 0.f};
  f32x4 acc[8];
#pragma unroll
  for (int n = 0; n < 8; ++n) acc[n] = z;
  const u16* arow = &As[(wave * 16 + lm) * LDA + quad * 8];
#pragma unroll
  for (int kc = 0; kc < 4; ++kc) {
    short8 af = *reinterpret_cast<const short8*>(arow + kc * 32);
#pragma unroll
    for (int n = 0; n < 8; ++n) {
      short8 bf = *reinterpret_cast<const short8*>(
          &Bs[(n * 16 + lm) * LDA + kc * 32 + quad * 8]);
      acc[n] = __builtin_amdgcn_mfma_f32_16x16x32_bf16(af, bf, acc[n], 0, 0, 0);
    }
  }
  // C/D layout: col = lane&15, row = quad*4 + reg
#pragma unroll
  for (int n = 0; n < 8; ++n) {
    int col = n * 16 + lm;
    float bv = bias ? bias[col] : 0.f;
#pragma unroll
    for (int r = 0; r < 4; ++r) {
      int row = m0 + wave * 16 + quad * 4 + r;
      if (row < M) {
        float v = acc[n][r] + bv;
        if (relu) v = fmaxf(v, 0.f);
        out[(size_t)row * 128 + col] = f2bf(v);
      }
    }
  }
}

// ONE bucketing pass for all layers; entry = edge index e == (src<<4)|slot_j.
// XCD-locality via STATIC partition: block b handles dst-range (b&7) over edge
// chunk (b>>3). With round-robin blockIdx->XCD dispatch, range r's slots/cnt
// lines live in one XCD's L2 (no cross-XCD line churn). Correct regardless of
// the actual mapping (partition is by blockIdx only); worst case is just slower.
__global__ __launch_bounds__(256) void k_fill(
    const int* __restrict__ edst, int* __restrict__ cnt,
    int* __restrict__ slots) {
  int r = blockIdx.x & (NXCD - 1);
  int bi = blockIdx.x >> 3;                 // 0..127
  int rlo = r * XRANGE, rhi = rlo + XRANGE;
  int tid = bi * 256 + threadIdx.x;         // 0..32767
  for (int e = tid; e < NNODES * DEGREE; e += 128 * 256) {
    int d = edst[e];
    if (d >= rlo && d < rhi) {
      int pos = atomicAdd(&cnt[d], 1);
      if (pos < CAP) slots[(size_t)d * CAP + pos] = e;
    }
  }
}

// wave per node: dinv[n]=rsqrt(1+sum_{kept} ew[src]); wsrc[n]=dinv[n]*ew[n]
// first=1 (layer 0): all ew==1 -> no gather needed
__global__ __launch_bounds__(256) void k_dinv(
    const int* __restrict__ cnt, const int* __restrict__ slots,
    const float* __restrict__ ew, float* __restrict__ dinv,
    float* __restrict__ wsrc, int keep, int first) {
  int n = (int)((blockIdx.x * blockDim.x + threadIdx.x) >> 6);
  int lane = threadIdx.x & 63;
  if (n >= NNODES) return;
  int c = min(cnt[n], CAP);
  float e = 0.f;
  if (first) {
    e = (lane < c) ? 1.f : 0.f;
  } else {
    u32 ent = 0;
    if (lane < c) ent = (u32)slots[(size_t)n * CAP + lane];
    if (lane < c && (ent & 15u) < (u32)keep) e = ew[ent >> 4];
  }
#pragma unroll
  for (int m = 32; m >= 1; m >>= 1) e += __shfl_xor(e, m, 64);
  float d = rsqrtf(1.0f + e);
  if (lane == 0) { dinv[n] = d; wsrc[n] = first ? d : d * ew[n]; }
}

// h[n] = relu( dinv[n]*sum_{kept} wsrc[src]*xw[src] + dinv[n]^2*xw[n] + b )
// keep<16: ballot + ds_permute compaction so gathers touch only kept edges.
// 8-deep software pipeline: 8 independent row loads in flight per wave.
__global__ __launch_bounds__(256) void k_agg(
    const u16* __restrict__ xwb, const int* __restrict__ cnt,
    const int* __restrict__ slots, const float* __restrict__ wsrc,
    const float* __restrict__ dinv, const float* __restrict__ bias,
    u16* __restrict__ hout, int keep) {
  int n = (int)((blockIdx.x * blockDim.x + threadIdx.x) >> 6);
  int lane = threadIdx.x & 63;
  if (n >= NNODES) return;
  int c = min(cnt[n], CAP);
  u32 e = 0;
  if (lane < c) e = (u32)slots[(size_t)n * CAP + lane];
  int kc; u32 ce;
  if (keep < 16) {
    bool valid = (lane < c) && ((e & 15u) < (u32)keep);
    u64 mask = __ballot(valid);
    kc = (int)__popcll(mask);
    u64 lt = ((u64)1 << lane) - 1;
    // collision-free permutation: valid lanes pack to [0,kc), invalid to (63..kc]
    int pos = valid ? (int)__popcll(mask & lt) : 63 - (int)__popcll((~mask) & lt);
    ce = (u32)__builtin_amdgcn_ds_permute(pos << 2, (int)e);
  } else { kc = c; ce = e; }
  int sl = 0; float wl = 0.f;
  if (lane < kc) {
    sl = (int)(ce >> 4);
    wl = wsrc[sl];
  }
  const u32* base = reinterpret_cast<const u32*>(xwb);
  float2 acc = make_float2(0.f, 0.f);
  int i = 0;
  for (; i + 8 <= kc; i += 8) {
    u32 r[8]; float w[8];
#pragma unroll
    for (int j = 0; j < 8; ++j) {
      int s = __shfl(sl, i + j, 64);
      w[j] = __shfl(wl, i + j, 64);
      r[j] = base[(size_t)s * 64 + lane];
    }
#pragma unroll
    for (int j = 0; j < 8; ++j) {
      float2 v = bf2x2(r[j]);
      acc.x = fmaf(w[j], v.x, acc.x);
      acc.y = fmaf(w[j], v.y, acc.y);
    }
  }
  for (; i + 4 <= kc; i += 4) {
    u32 r[4]; float w[4];
#pragma unroll
    for (int j = 0; j < 4; ++j) {
      int s = __shfl(sl, i + j, 64);
      w[j] = __shfl(wl, i + j, 64);
      r[j] = base[(size_t)s * 64 + lane];
    }
#pragma unroll
    for (int j = 0; j < 4; ++j) {
      float2 v = bf2x2(r[j]);
      acc.x = fmaf(w[j], v.x, acc.x);
      acc.y = fmaf(w[j], v.y, acc.y);
    }
  }
  for (; i < kc; ++i) {
    int s = __shfl(sl, i, 64);
    float w = __shfl(wl, i, 64);
    float2 v = bf2x2(base[(size_t)s * 64 + lane]);
    acc.x = fmaf(w, v.x, acc.x);
    acc.y = fmaf(w, v.y, acc.y);
  }
  float di = dinv[n];
  float2 self = bf2x2(base[(size_t)n * 64 + lane]);
  float2 b = reinterpret_cast<const float2*>(bias)[lane];
  float rx = fmaxf(fmaf(di, acc.x, fmaf(di * di, self.x, b.x)), 0.f);
  float ry = fmaxf(fmaf(di, acc.y, fmaf(di * di, self.y, b.y)), 0.f);
  reinterpret_cast<u32*>(hout + (size_t)n * 128)[lane] = pack2(rx, ry);
}

// layer-0 score: ew[n] = clip(tanh(16*dot(relu(agg0*weg0+beg0), wsc0)+bsc0),0,1)
__global__ void k_score0(const float* __restrict__ agg0, const float* __restrict__ weg,
                         const float* __restrict__ beg, const float* __restrict__ wsc,
                         const float* __restrict__ bsc, float* __restrict__ ew) {
  int n = blockIdx.x * blockDim.x + threadIdx.x;
  if (n >= NNODES) return;
  float a = agg0[n];
  float s = 0.f;
  for (int k = 0; k < 128; ++k) {
    float e = fmaxf(fmaf(a, weg[k], beg[k]), 0.f);
    s = fmaf(e, wsc[k], s);
  }
  float sc = tanhf(fmaf(16.f, s, bsc[0]));
  ew[n] = fminf(fmaxf(sc, 0.f), 1.f);
}

// layer-1 score from ea2 (bf16): ew[n] = clip(tanh(scale*dot(ea2[n], wsc1)+bsc1),0,1)
__global__ __launch_bounds__(256) void k_score1(
    const u16* __restrict__ ea2, const float* __restrict__ wsc,
    const float* __restrict__ bsc, float scale, float* __restrict__ ew) {
  int wave = (int)((blockIdx.x * blockDim.x + threadIdx.x) >> 6);
  int lane = threadIdx.x & 63;
  if (wave >= NNODES) return;
  float2 v = bf2x2(reinterpret_cast<const u32*>(ea2 + (size_t)wave * 128)[lane]);
  float2 w = reinterpret_cast<const float2*>(wsc)[lane];
  float s = fmaf(v.x, w.x, v.y * w.y);
#pragma unroll
  for (int m = 32; m >= 1; m >>= 1) s += __shfl_xor(s, m, 64);
  if (lane == 0) {
    float sc = tanhf(fmaf(scale, s, bsc[0]));
    ew[wave] = fminf(fmaxf(sc, 0.f), 1.f);
  }
}

// pooling stage A: 16 slices per graph -> partial max/sum per feature (bf16 input)
__global__ __launch_bounds__(256) void k_poolA(
    const u16* __restrict__ h, const int* __restrict__ batch,
    float* __restrict__ pmax, float* __restrict__ psum) {
  __shared__ float smx[256], ssm[256];
  int g = blockIdx.x >> 4, sl = blockIdx.x & 15;
  int lo = lowerb(batch, NNODES, g);
  int hi = lowerb(batch, NNODES, g + 1);
  int len = hi - lo;
  int start = lo + (len * sl) / 16;
  int end = lo + (len * (sl + 1)) / 16;
  int f = threadIdx.x & 127, half = threadIdx.x >> 7;
  float mx = -3.402823466e38f, sm = 0.f;
  for (int n = start + half; n < end; n += 2) {
    float v = bf2f(h[(size_t)n * 128 + f]);
    mx = fmaxf(mx, v);
    sm += v;
  }
  smx[threadIdx.x] = mx; ssm[threadIdx.x] = sm;
  __syncthreads();
  if (threadIdx.x < 128) {
    mx = fmaxf(smx[threadIdx.x], smx[threadIdx.x + 128]);
    sm = ssm[threadIdx.x] + ssm[threadIdx.x + 128];
    pmax[(size_t)blockIdx.x * 128 + threadIdx.x] = mx;
    psum[(size_t)blockIdx.x * 128 + threadIdx.x] = sm;
  }
}

// pooling stage B: combine 16 slices, accumulate [gmax|gmean|gsum] into out
__global__ void k_poolB(const float* __restrict__ pmax, const float* __restrict__ psum,
                        const int* __restrict__ batch, float* __restrict__ out) {
  int g = blockIdx.x, f = threadIdx.x;
  float mx = -3.402823466e38f, sm = 0.f;
  for (int s = 0; s < 16; ++s) {
    mx = fmaxf(mx, pmax[(size_t)(g * 16 + s) * 128 + f]);
    sm += psum[(size_t)(g * 16 + s) * 128 + f];
  }
  int lo = lowerb(batch, NNODES, g);
  int hi = lowerb(batch, NNODES, g + 1);
  float cntf = (float)(hi - lo);
  out[g * 384 + f] += mx;
  out[g * 384 + 128 + f] += sm / cntf;
  out[g * 384 + 256 + f] += sm;
}

extern "C" void kernel_launch(void* const* d_in, const int* in_sizes, int n_in,
                              void* d_out, int out_size, void* d_ws, size_t ws_size,
                              hipStream_t stream) {
  const float* x     = (const float*)d_in[0];
  const float* eattr = (const float*)d_in[1];
  const int*   edst  = (const int*)d_in[3];
  const int*   batch = (const int*)d_in[4];
  const float* Wg0 = (const float*)d_in[5];  const float* bg0 = (const float*)d_in[6];
  const float* Wg1 = (const float*)d_in[7];  const float* bg1 = (const float*)d_in[8];
  const float* Wg2 = (const float*)d_in[9];  const float* bg2 = (const float*)d_in[10];
  const float* We0 = (const float*)d_in[11]; const float* be0 = (const float*)d_in[12];
  const float* We1 = (const float*)d_in[13]; const float* be1 = (const float*)d_in[14];
  const float* Ws0 = (const float*)d_in[15]; const float* bs0 = (const float*)d_in[16];
  const float* Ws1 = (const float*)d_in[17]; const float* bs1 = (const float*)d_in[18];
  float* out = (float*)d_out;

  char* ws = (char*)d_ws;
  const size_t NBH = (size_t)NNODES * 128 * 2;   // 12.8 MB bf16 node-feature block
  size_t off = 0;
  auto alloc = [&](size_t bytes) { void* p = ws + off; off = (off + bytes + 255) & ~(size_t)255; return p; };
  u16*   Xb    = (u16*)alloc(NBH);
  u16*   XWb   = (u16*)alloc(NBH);
  u16*   Hb    = (u16*)alloc(NBH);
  u16*   Wtb   = (u16*)alloc(4 * 128 * 128 * 2);
  int*   slots = (int*)alloc((size_t)NNODES * CAP * 4);
  int*   cnt   = (int*)alloc((size_t)NNODES * 4);
  float* agg0  = (float*)alloc((size_t)NNODES * 4);
  float* ew    = (float*)alloc((size_t)NNODES * 4);
  float* dinv  = (float*)alloc((size_t)NNODES * 4);
  float* wsrc  = (float*)alloc((size_t)NNODES * 4);
  float* pmax  = (float*)alloc((size_t)NGRAPH * 16 * 128 * 4);
  float* psum  = (float*)alloc((size_t)NGRAPH * 16 * 128 * 4);

  hipMemsetAsync(d_out, 0, (size_t)out_size * sizeof(float), stream);
  hipMemsetAsync(cnt, 0, (size_t)NNODES * 4, stream);
  int nblkN = (NNODES + 255) / 256;
  k_init<<<(NNODES * 32 + 255) / 256, 256, 0, stream>>>(eattr, x, ew, agg0, Xb);
  k_cvtW4<<<(4 * 16384 + 255) / 256, 256, 0, stream>>>(Wg0, Wg1, Wg2, We1, Wtb);
  // ONE bucketing pass for all 3 layers (edge sets are slot-prefixes), static XCD ranges
  k_fill<<<1024, 256, 0, stream>>>(edst, cnt, slots);

  const float* bg[3] = {bg0, bg1, bg2};
  const int keep[3] = {16, 8, 4};
  const int ntile = (NNODES + 63) / 64;   // 782
  const u16* hin = Xb;
  for (int L = 0; L < 3; ++L) {
    k_gemm_mfma<<<ntile, 256, 0, stream>>>(hin, Wtb + (size_t)L * 16384, nullptr, XWb,
                                           NNODES, 0, 0, 1.f, nullptr, nullptr, nullptr);
    k_dinv<<<(NNODES + 3) / 4, 256, 0, stream>>>(cnt, slots, ew, dinv, wsrc,
                                                 keep[L], L == 0 ? 1 : 0);
    k_agg<<<(NNODES + 3) / 4, 256, 0, stream>>>(XWb, cnt, slots, wsrc, dinv, bg[L],
                                                Hb, keep[L]);
    k_poolA<<<NGRAPH * 16, 256, 0, stream>>>(Hb, batch, pmax, psum);
    k_poolB<<<NGRAPH, 128, 0, stream>>>(pmax, psum, batch, out);
    if (L == 0) {
      k_score0<<<nblkN, 256, 0, stream>>>(agg0, We0, be0, Ws0, bs0, ew);
    } else if (L == 1) {
      // ea2 = relu((8*ea1) @ W_eg1 + b_eg1), ea1 regenerated from agg0 in-kernel
      k_gemm_mfma<<<ntile, 256, 0, stream>>>(nullptr, Wtb + 3 * 16384, be1, XWb,
                                             NNODES, 1, 1, 8.f, agg0, We0, be0);
      // ew for layer 2: clip(tanh(8*ea2.wsc1 + bsc1))
      k_score1<<<(NNODES + 3) / 4, 256, 0, stream>>>(XWb, Ws1, bs1, 8.f, ew);
    }
    hin = Hb;
  }
}